// Round 1
// baseline (1355.111 us; speedup 1.0000x reference)
//
#include <hip/hip_runtime.h>
#include <hip/hip_bf16.h>

// GCNConvDiagDGL: out = segment_sum( (features*W)[src], dst, N )
// N=100000 nodes, E=1600000 edges, D=64 feats, fp32.
//
// Strategy: atomic scatter-add. 16 threads per edge, each thread handles a
// float4 chunk of the 64-wide feature row. unsafeAtomicAdd -> HW
// global_atomic_add_f32 (no CAS loop).

#define D_FEAT 64

__global__ void gcn_scatter_kernel(const float* __restrict__ feat,
                                   const float* __restrict__ W,
                                   const int* __restrict__ src,
                                   const int* __restrict__ dst,
                                   float* __restrict__ out,
                                   int n_edges) {
    const long long gid = (long long)blockIdx.x * blockDim.x + threadIdx.x;
    const long long total = (long long)n_edges * 16;  // 16 threads / edge
    if (gid >= total) return;

    const int e = (int)(gid >> 4);        // edge index
    const int t = (int)(gid & 15);        // chunk index within row (4 floats)

    const int s = src[e];
    const int d = dst[e];

    const float4 f = *reinterpret_cast<const float4*>(feat + (long long)s * D_FEAT + t * 4);
    const float4 w = *reinterpret_cast<const float4*>(W + t * 4);

    float* o = out + (long long)d * D_FEAT + t * 4;
    unsafeAtomicAdd(o + 0, f.x * w.x);
    unsafeAtomicAdd(o + 1, f.y * w.y);
    unsafeAtomicAdd(o + 2, f.z * w.z);
    unsafeAtomicAdd(o + 3, f.w * w.w);
}

extern "C" void kernel_launch(void* const* d_in, const int* in_sizes, int n_in,
                              void* d_out, int out_size, void* d_ws, size_t ws_size,
                              hipStream_t stream) {
    const float* feat = (const float*)d_in[0];   // [N, 64]
    const float* W    = (const float*)d_in[1];   // [64]
    const int*   src  = (const int*)d_in[2];     // [E]
    const int*   dst  = (const int*)d_in[3];     // [E]
    float* out = (float*)d_out;                  // [N, 64]

    const int n_edges = in_sizes[2];

    // Zero the output (harness poisons it with 0xAA; we accumulate with atomics).
    hipMemsetAsync(d_out, 0, (size_t)out_size * sizeof(float), stream);

    const long long total_threads = (long long)n_edges * 16;
    const int block = 256;
    const long long grid = (total_threads + block - 1) / block;
    gcn_scatter_kernel<<<(dim3)(unsigned)grid, block, 0, stream>>>(
        feat, W, src, dst, out, n_edges);
}

// Round 2
// 240.930 us; speedup vs baseline: 5.6245x; 5.6245x over previous
//
#include <hip/hip_runtime.h>
#include <hip/hip_bf16.h>

// GCNConvDiagDGL: out = segment_sum( (features*W)[src], dst, N )
// N=100000, E=1600000, D=64, fp32.
//
// Round 1 -> 2: atomic scatter (1.6 GB atomic write-through, 1353us) replaced
// by on-device dst-CSR build + pull-mode gather:
//   1. histogram of dst          (int atomics, cheap)
//   2. exclusive scan (2-phase)  -> offsets[N+1]
//   3. counting-sort src by dst  -> sorted_src[E]
//   4. gather: 1 wave/node, lane=feature, sum rows, *W, single store.
// Output written exactly once; zero fp atomics.

#define D 64

// ---------------- block-wide exclusive scan helper ----------------
// NW = number of waves in the block (blockDim.x / 64), must be <= 64.
template <int NW>
__device__ inline int block_excl_scan(int val, int tid, int* lds_wsum, int* total) {
    const int lane = tid & 63;
    const int wid  = tid >> 6;
    int v = val;
#pragma unroll
    for (int d = 1; d < 64; d <<= 1) {
        int t = __shfl_up(v, d);
        if (lane >= d) v += t;
    }
    if (lane == 63) lds_wsum[wid] = v;
    __syncthreads();
    if (wid == 0) {
        int s = (lane < NW) ? lds_wsum[lane] : 0;
#pragma unroll
        for (int d = 1; d < NW; d <<= 1) {
            int t = __shfl_up(s, d);
            if (lane >= d) s += t;
        }
        if (lane < NW) lds_wsum[lane] = s;
    }
    __syncthreads();
    const int base = wid ? lds_wsum[wid - 1] : 0;
    *total = lds_wsum[NW - 1];
    return base + v - val;  // exclusive
}

// ---------------- CSR build ----------------
__global__ void hist_kernel(const int* __restrict__ dst, int* __restrict__ counts,
                            int n_edges) {
    int e = blockIdx.x * blockDim.x + threadIdx.x;
    if (e < n_edges) atomicAdd(&counts[dst[e]], 1);
}

// Phase A: per-block local exclusive scan of counts -> offsets (block-local),
// block totals -> partials[b].
__global__ void __launch_bounds__(1024) scanA_kernel(const int* __restrict__ counts,
                                                     int* __restrict__ offsets,
                                                     int* __restrict__ partials, int n) {
    __shared__ int wsum[16];
    const int tid = threadIdx.x;
    const int i   = blockIdx.x * 1024 + tid;
    const int v   = (i < n) ? counts[i] : 0;
    int total;
    const int ex = block_excl_scan<16>(v, tid, wsum, &total);
    if (i < n) offsets[i] = ex;
    if (tid == 0) partials[blockIdx.x] = total;
}

// Phase B: single block scans the (<=128) partials in place (exclusive),
// writes grand total to offsets[n].
__global__ void __launch_bounds__(128) scanB_kernel(int* __restrict__ partials,
                                                    int* __restrict__ offsets,
                                                    int nblk, int n) {
    __shared__ int wsum[2];
    const int tid = threadIdx.x;
    const int v   = (tid < nblk) ? partials[tid] : 0;
    int total;
    const int ex = block_excl_scan<2>(v, tid, wsum, &total);
    if (tid < nblk) partials[tid] = ex;
    if (tid == 0) offsets[n] = total;
}

// Phase C: add block bases to offsets.
__global__ void __launch_bounds__(1024) scanC_kernel(int* __restrict__ offsets,
                                                     const int* __restrict__ partials,
                                                     int n) {
    const int i = blockIdx.x * 1024 + threadIdx.x;
    if (i < n) offsets[i] += partials[blockIdx.x];
}

// Counting sort: fill buckets from the end using atomicSub on counts
// (counts[d] currently = degree(d); no second memset needed).
__global__ void scatter_kernel(const int* __restrict__ src, const int* __restrict__ dst,
                               const int* __restrict__ offsets, int* __restrict__ counts,
                               int* __restrict__ sorted_src, int n_edges) {
    int e = blockIdx.x * blockDim.x + threadIdx.x;
    if (e >= n_edges) return;
    const int d   = dst[e];
    const int old = atomicSub(&counts[d], 1);  // old in [1..deg]
    sorted_src[offsets[d] + old - 1] = src[e];
}

// ---------------- pull-mode gather ----------------
// One wave per node; lane = feature index. 4 waves / 256-thread block.
__global__ void __launch_bounds__(256) gather_kernel(const float* __restrict__ feat,
                                                     const float* __restrict__ W,
                                                     const int* __restrict__ offsets,
                                                     const int* __restrict__ sorted_src,
                                                     float* __restrict__ out, int n_nodes) {
    const int wid  = threadIdx.x >> 6;
    const int lane = threadIdx.x & 63;
    const int node = blockIdx.x * 4 + wid;
    if (node >= n_nodes) return;

    const int beg = offsets[node];
    const int end = offsets[node + 1];

    float acc = 0.0f;
    int e = beg;
    // 4-wide unroll: 4 independent feature-row loads in flight.
    for (; e + 4 <= end; e += 4) {
        const int s0 = sorted_src[e + 0];
        const int s1 = sorted_src[e + 1];
        const int s2 = sorted_src[e + 2];
        const int s3 = sorted_src[e + 3];
        const float f0 = feat[(long long)s0 * D + lane];
        const float f1 = feat[(long long)s1 * D + lane];
        const float f2 = feat[(long long)s2 * D + lane];
        const float f3 = feat[(long long)s3 * D + lane];
        acc += (f0 + f1) + (f2 + f3);
    }
    for (; e < end; ++e) {
        acc += feat[(long long)sorted_src[e] * D + lane];
    }

    out[(long long)node * D + lane] = acc * W[lane];
}

// ---------------- fallback: round-1 atomic scatter ----------------
__global__ void fallback_scatter(const float* __restrict__ feat, const float* __restrict__ W,
                                 const int* __restrict__ src, const int* __restrict__ dst,
                                 float* __restrict__ out, int n_edges) {
    const long long gid = (long long)blockIdx.x * blockDim.x + threadIdx.x;
    if (gid >= (long long)n_edges * 16) return;
    const int e = (int)(gid >> 4);
    const int t = (int)(gid & 15);
    const float4 f = *reinterpret_cast<const float4*>(feat + (long long)src[e] * D + t * 4);
    const float4 w = *reinterpret_cast<const float4*>(W + t * 4);
    float* o = out + (long long)dst[e] * D + t * 4;
    unsafeAtomicAdd(o + 0, f.x * w.x);
    unsafeAtomicAdd(o + 1, f.y * w.y);
    unsafeAtomicAdd(o + 2, f.z * w.z);
    unsafeAtomicAdd(o + 3, f.w * w.w);
}

extern "C" void kernel_launch(void* const* d_in, const int* in_sizes, int n_in,
                              void* d_out, int out_size, void* d_ws, size_t ws_size,
                              hipStream_t stream) {
    const float* feat = (const float*)d_in[0];
    const float* W    = (const float*)d_in[1];
    const int*   src  = (const int*)d_in[2];
    const int*   dst  = (const int*)d_in[3];
    float* out = (float*)d_out;

    const int n_edges = in_sizes[2];
    const int n_nodes = out_size / D;
    const int nblk    = (n_nodes + 1023) / 1024;

    // ws layout: counts[N] | offsets[N+1] | partials[nblk] | sorted_src[E]
    const size_t need = ((size_t)n_nodes + (size_t)n_nodes + 1 + (size_t)nblk +
                         (size_t)n_edges) * sizeof(int);
    if (ws_size < need || nblk > 128) {
        // fallback: atomic scatter (correct, slower)
        hipMemsetAsync(d_out, 0, (size_t)out_size * sizeof(float), stream);
        const long long total = (long long)n_edges * 16;
        fallback_scatter<<<(unsigned)((total + 255) / 256), 256, 0, stream>>>(
            feat, W, src, dst, out, n_edges);
        return;
    }

    int* counts     = (int*)d_ws;
    int* offsets    = counts + n_nodes;
    int* partials   = offsets + n_nodes + 1;
    int* sorted_src = partials + nblk;

    hipMemsetAsync(counts, 0, (size_t)n_nodes * sizeof(int), stream);

    hist_kernel<<<(n_edges + 255) / 256, 256, 0, stream>>>(dst, counts, n_edges);
    scanA_kernel<<<nblk, 1024, 0, stream>>>(counts, offsets, partials, n_nodes);
    scanB_kernel<<<1, 128, 0, stream>>>(partials, offsets, nblk, n_nodes);
    scanC_kernel<<<nblk, 1024, 0, stream>>>(offsets, partials, n_nodes);
    scatter_kernel<<<(n_edges + 255) / 256, 256, 0, stream>>>(src, dst, offsets, counts,
                                                              sorted_src, n_edges);
    gather_kernel<<<(n_nodes + 3) / 4, 256, 0, stream>>>(feat, W, offsets, sorted_src,
                                                         out, n_nodes);
}